// Round 1
// baseline (1868.621 us; speedup 1.0000x reference)
//
#include <hip/hip_runtime.h>
#include <stdint.h>

// ---------------- problem constants ----------------
#define HW    576
#define CIN   48
#define NB    1024

// output element offsets (flat fp32: center,kp,reg,off,norm,pix)
#define O_CENTER 0L
#define O_KP     589824L
#define O_REG    2949120L
#define O_OFF    7667712L
#define O_NORM   12386304L
#define O_PIX    12394496L

// workspace byte offsets (total 174,752 B -- under the R2-proven 185,856 B)
#define WS_A1    0        // bf16 conv1 A-table [9sh][3k16][2g][96row][8ci] = 82944 B
#define WS_W2A   82944    // bf16 conv2 A-table [6k16][2g][32oc][8k]       = 6144 B
#define WS_B1A   89088    // fp32 folded bias1 [96]
#define WS_B2A   89472    // fp32 bias2 [32]
#define WS_WKPT  89600    // fp32 kp conv1 weights [ci48][k9][mid24] = 41472 B
#define WS_B1KP  131072   // fp32 [24]
#define WS_W2KP  131168   // fp32 [4][24]
#define WS_B2KP  131552   // fp32 [4]
#define WS_WOFFT 131584   // fp32 off conv1 weights [ci48][k9][mid24] = 41472 B
#define WS_B1OFF 173056   // fp32 [24]
#define WS_W2OFF 173152   // fp32 [16][24]
#define WS_B2OFF 174688   // fp32 [16]

typedef short bf16x8 __attribute__((ext_vector_type(8)));
typedef float f32x16 __attribute__((ext_vector_type(16)));

union U4B  { uint4 q; bf16x8 v; };
union U16Q { uint16_t u[8]; uint4 q; };
union U4Q  { uint16_t u[4]; uint2 q; };

__device__ __forceinline__ bf16x8 as_bf(uint4 q){ U4B u; u.q = q; return u.v; }
__device__ __forceinline__ uint16_t f2b(float f){
  union { float f; uint32_t i; } x; x.f = f;
  uint32_t r = x.i + 0x7FFFu + ((x.i >> 16) & 1u);   // RNE
  return (uint16_t)(r >> 16);
}

struct P32 {
  const float* w1[4]; const float* b1[4]; const float* g[4]; const float* be[4];
  const float* m[4];  const float* v[4];  const float* w2[4]; const float* b2[4];
};

// oc (0..20) -> head, local channel. order: center(1), kp(4), reg(8), off(8)
__device__ __forceinline__ void oc_decode(int oc, int& h, int& ch){
  if (oc == 0){ h = 0; ch = 0; }
  else if (oc < 5){ h = 1; ch = oc - 1; }
  else if (oc < 13){ h = 2; ch = oc - 5; }
  else { h = 3; ch = oc - 13; }
}

// ---------------- K0: build all tables in ws ----------------
__global__ void prep_kernel(P32 P, char* __restrict__ wsb){
  const int tid = threadIdx.x;
  __shared__ float sc[96], bfold[96];
  if (tid < 96){
    int h = tid / 24, o = tid % 24;
    float s = P.g[h][o] / sqrtf(P.v[h][o] + 1e-5f);   // R2's known-good fold
    sc[tid] = s;
    bfold[tid] = (P.b1[h][o] - P.m[h][o]) * s + P.be[h][o];
  }
  __syncthreads();
  uint16_t* A1 = (uint16_t*)(wsb + WS_A1);
  for (int t = tid; t < 41472; t += 256){
    int j = t & 7, slot = t >> 3;
    int row = slot % 96, sk = slot / 96;
    int g = sk & 1, k3 = (sk >> 1) % 3, sh = (sk >> 1) / 3;
    int ci = k3*16 + g*8 + j;
    int h = row / 24, o = row % 24;
    A1[t] = f2b(P.w1[h][(o*CIN + ci)*9 + sh] * sc[row]);
  }
  uint16_t* W2A = (uint16_t*)(wsb + WS_W2A);
  for (int t = tid; t < 3072; t += 256){
    int j = t & 7, slot = t >> 3;
    int oc = slot & 31, kg = slot >> 5;
    int k = kg*8 + j;
    float val = 0.f;
    if (oc < 21){
      int h, ch; oc_decode(oc, h, ch);
      int hk = k / 24, o = k % 24;
      if (hk == h) val = P.w2[h][ch*24 + o];
    }
    W2A[t] = f2b(val);
  }
  float* B1A = (float*)(wsb + WS_B1A);
  if (tid < 96) B1A[tid] = bfold[tid];
  float* B2A = (float*)(wsb + WS_B2A);
  if (tid < 32){
    float v = 0.f;
    if (tid < 21){ int h, ch; oc_decode(tid, h, ch); v = P.b2[h][ch]; }
    B2A[tid] = v;
  }
  // kp exact tables (fp32), [ci][k][mid]
  float* WKPT = (float*)(wsb + WS_WKPT);
  for (int t = tid; t < 10368; t += 256){
    int o = t % 24, k = (t/24) % 9, ci = t / 216;
    WKPT[t] = P.w1[1][(o*CIN + ci)*9 + k] * sc[24 + o];
  }
  if (tid < 24) ((float*)(wsb + WS_B1KP))[tid] = bfold[24 + tid];
  if (tid < 96) ((float*)(wsb + WS_W2KP))[tid] = P.w2[1][tid];
  if (tid < 4)  ((float*)(wsb + WS_B2KP))[tid] = P.b2[1][tid];
  // off exact tables (fp32), [ci][k][mid]
  float* WOFFT = (float*)(wsb + WS_WOFFT);
  for (int t = tid; t < 10368; t += 256){
    int o = t % 24, k = (t/24) % 9, ci = t / 216;
    WOFFT[t] = P.w1[3][(o*CIN + ci)*9 + k] * sc[72 + o];
  }
  if (tid < 24)  ((float*)(wsb + WS_B1OFF))[tid] = bfold[72 + tid];
  for (int t = tid; t < 384; t += 256) ((float*)(wsb + WS_W2OFF))[t] = P.w2[3][t];
  if (tid < 16)  ((float*)(wsb + WS_B2OFF))[tid] = P.b2[3][tid];
}

// ---------------- K1: fused MFMA conv + exact kp argmax/offsets ----------------
// LDS layout (phased aliasing):
//   [0, 60000)      phase A: bf16 image [6cib][625][16B]    (dead after main loop)
//   [0, 55296)      phase B: per-wave ybuf (9 x 6144)
//   [55296, 64512)  heat[4][576] fp32 kp logits (written phase B, read C)
//   [64512, 73728)  cand[4][576] int candidate pixel lists
//   [73728, 73744)  cnt[4]
//   [73744, 73776)  best[4] u64 packed (keyed-float << 32 | (1023-p))
// 73,792 B total -> still 2 blocks/CU (147,584 <= 163,840).
//
// Candidate margin: exact argmax p* satisfies bf16heat(p*) >= bf16max - 2e where
// e = max |bf16logit - exactlogit|. Observed pipeline absmax vs reference (raw
// reg/off heads, same conv structure/scale) = 0.0078 -> e ~ 0.008. M = 0.1875
// gives ~12x safety on 2e. cand[] is sized 576/head: no overflow path exists.
__global__ __launch_bounds__(576) void conv_main(
    const float* __restrict__ feat, const char* __restrict__ wsb,
    float* __restrict__ out)
{
  __shared__ __align__(16) char smem[73792];
  const int b = blockIdx.x, tid = threadIdx.x;
  const int wave = tid >> 6, lane = tid & 63;
  const int q = lane >> 5, l31 = lane & 31;

  float* heatL = (float*)(smem + 55296);
  int*   candL = (int*)(smem + 64512);
  int*   cntL  = (int*)(smem + 73728);
  unsigned long long* bestL = (unsigned long long*)(smem + 73744);

  if (tid < 4){ cntL[tid] = 0; bestL[tid] = 0ULL; }

  if (tid < 294){                                 // zero border row y'=0, col x'=0
    int cib = tid / 49, r = tid % 49;
    int slot = cib*625 + ((r < 25) ? r : (r - 24)*25);
    *(uint4*)(smem + slot*16) = make_uint4(0,0,0,0);
  }
  {
    const float* fbs = feat + (size_t)b * (CIN*HW);
    int p = tid, py = p / 24, px = p % 24;
    int sbase = (py+1)*25 + (px+1);
    for (int cib = 0; cib < 6; ++cib){
      U16Q t8;
      #pragma unroll
      for (int j = 0; j < 8; ++j) t8.u[j] = f2b(fbs[(cib*8 + j)*HW + p]);
      *(uint4*)(smem + (cib*625 + sbase)*16) = t8.q;
    }
  }
  __syncthreads();

  f32x16 acc[3][2] = {};
  const int p0 = wave*64 + l31, p1 = p0 + 32;
  const int py0 = p0/24, px0 = p0%24, py1 = p1/24, px1 = p1%24;
  const uint4* A1 = (const uint4*)(wsb + WS_A1);
  const uint4 zz = make_uint4(0,0,0,0);

  for (int sh = 0; sh < 9; ++sh){
    const int ky = sh / 3, kx = sh % 3;
    const int yb0 = py0 + ky, xb0 = px0 + kx;
    const int yb1 = py1 + ky, xb1 = px1 + kx;
    const bool v0 = (yb0 < 25) && (xb0 < 25);
    const bool v1 = (yb1 < 25) && (xb1 < 25);
    const int so0 = yb0*25 + xb0, so1 = yb1*25 + xb1;
    #pragma unroll
    for (int k3 = 0; k3 < 3; ++k3){
      const int cib = k3*2 + q;
      uint4 r0 = *(const uint4*)(smem + (cib*625 + (v0 ? so0 : 0))*16);
      uint4 r1 = *(const uint4*)(smem + (cib*625 + (v1 ? so1 : 0))*16);
      r0 = v0 ? r0 : zz;
      r1 = v1 ? r1 : zz;
      const bf16x8 bf0 = as_bf(r0), bf1 = as_bf(r1);
      const int abase = ((sh*3 + k3)*2 + q)*96 + l31;
      #pragma unroll
      for (int mt = 0; mt < 3; ++mt){
        const bf16x8 af = as_bf(A1[abase + mt*32]);
        acc[mt][0] = __builtin_amdgcn_mfma_f32_32x32x16_bf16(af, bf0, acc[mt][0], 0, 0, 0);
        acc[mt][1] = __builtin_amdgcn_mfma_f32_32x32x16_bf16(af, bf1, acc[mt][1], 0, 0, 0);
      }
    }
  }
  __syncthreads();                                // image dead; reuse LDS

  const float* B1A = (const float*)(wsb + WS_B1A);
  const float* B2A = (const float*)(wsb + WS_B2A);
  const uint4* W2A = (const uint4*)(wsb + WS_W2A);
  char* ybuf = smem + wave*6144;

  #pragma unroll
  for (int st2 = 0; st2 < 2; ++st2){
    const int p = st2 ? p1 : p0;
    #pragma unroll
    for (int mt = 0; mt < 3; ++mt){
      #pragma unroll
      for (int rg = 0; rg < 4; ++rg){
        const int chanbase = mt*32 + rg*8 + q*4;
        const float* bp = B1A + chanbase;
        U4Q t4;
        #pragma unroll
        for (int r0 = 0; r0 < 4; ++r0){
          float y = acc[mt][st2][rg*4 + r0] + bp[r0];
          t4.u[r0] = f2b(fmaxf(y, 0.f));
        }
        *(uint2*)(ybuf + ((mt*4 + rg)*32 + l31)*16 + q*8) = t4.q;
      }
    }
    f32x16 c2 = {};
    #pragma unroll
    for (int k6 = 0; k6 < 6; ++k6){
      const bf16x8 yf = as_bf(*(const uint4*)(ybuf + ((k6*2 + q)*32 + l31)*16));
      const bf16x8 wf = as_bf(W2A[(k6*2 + q)*32 + l31]);
      c2 = __builtin_amdgcn_mfma_f32_32x32x16_bf16(wf, yf, c2, 0, 0, 0);
    }
    #pragma unroll
    for (int r = 0; r < 16; ++r){
      const int oc = (r & 3) + 8*(r >> 2) + 4*q;
      if (oc < 21){
        float v = c2[r] + B2A[oc];
        long base; int sig;
        if (oc == 0){ base = O_CENTER + (long)b*HW; sig = 1; }
        else if (oc < 5){
          base = O_KP + ((long)b*4 + (oc-1))*HW; sig = 1;
          heatL[(oc-1)*HW + p] = v;              // stash raw logit for argmax
        }
        else if (oc < 13){ base = O_REG + ((long)b*8 + (oc-5))*HW; sig = 0; }
        else { base = O_OFF + ((long)b*8 + (oc-13))*HW; sig = 0; }
        out[base + p] = sig ? (1.f / (1.f + __expf(-v))) : v;
      }
    }
  }
  __syncthreads();                                // heat[4][576] complete

  // ---- Phase C: per-n bf16-heat max + candidate collection ----
  if (tid < 256){
    const int n = tid >> 6, ln = tid & 63;
    float mx = -1e30f;
    #pragma unroll
    for (int j = 0; j < 9; ++j) mx = fmaxf(mx, heatL[n*HW + j*64 + ln]);
    #pragma unroll
    for (int off = 32; off >= 1; off >>= 1)
      mx = fmaxf(mx, __shfl_xor(mx, off, 64));
    const float thr = mx - 0.1875f;
    #pragma unroll
    for (int j = 0; j < 9; ++j){
      const int p = j*64 + ln;
      if (heatL[n*HW + p] >= thr){
        const int slot = atomicAdd(&cntL[n], 1);
        candL[n*HW + slot] = p;
      }
    }
  }
  __syncthreads();

  // ---- Phase D: exact fp32 kp logits at candidates (18 teams of 32 lanes) ----
  // Bit-identical math to the old full-scan kernel: per mid o, fmaf over
  // (ci ascending, k ascending); OOB skip == fmaf(0,w,acc). Tie-break via
  // packed u64 atomicMax: value desc, then smallest pixel index.
  const int team = tid >> 5, tl = tid & 31;
  const int K0 = cntL[0], K1 = cntL[1], K2 = cntL[2];
  const int s2c = K0 + K1, s3c = s2c + K2, Ktot = s3c + cntL[3];
  const float* fb = feat + (size_t)b * (CIN*HW);
  {
    const float* WKPT = (const float*)(wsb + WS_WKPT);
    const float* B1KP = (const float*)(wsb + WS_B1KP);
    const float* W2KP = (const float*)(wsb + WS_W2KP);
    const float* B2KP = (const float*)(wsb + WS_B2KP);
    for (int job = team; job < Ktot; job += 18){
      int n, slot;
      if (job < K0){ n = 0; slot = job; }
      else if (job < s2c){ n = 1; slot = job - K0; }
      else if (job < s3c){ n = 2; slot = job - s2c; }
      else { n = 3; slot = job - s3c; }
      const int p = candL[n*HW + slot], py = p / 24, px = p % 24;
      float ymid = 0.f;
      if (tl < 24){
        float s = 0.f;
        for (int ci = 0; ci < CIN; ++ci){
          const float* wv = WKPT + ci*216 + tl;
          const float* xb = fb + ci*HW;
          #pragma unroll
          for (int k = 0; k < 9; ++k){
            const int yy = py + k/3 - 1, xx = px + k%3 - 1;
            if (yy >= 0 && yy < 24 && xx >= 0 && xx < 24)
              s = fmaf(xb[yy*24 + xx], wv[k*24], s);
          }
        }
        ymid = fmaxf(s + B1KP[tl], 0.f);
      }
      float v = B2KP[n];
      for (int o = 0; o < 24; ++o)
        v = fmaf(__shfl(ymid, o, 32), W2KP[n*24 + o], v);
      if (tl == 0){
        union { float f; uint32_t u; } cv; cv.f = v;
        const uint32_t key = cv.u ^ (uint32_t)(((int32_t)cv.u >> 31) | (int32_t)0x80000000);
        const unsigned long long pk =
            ((unsigned long long)key << 32) | (unsigned)(1023 - p);
        atomicMax(&bestL[n], pk);
      }
    }
  }
  __syncthreads();

  // ---- Phase E: exact off-head at winners, norm/pix (teams 0..3 -> n) ----
  if (team < 4){
    const int n = team;
    const int p = 1023 - (int)(bestL[n] & 0xFFFFFFFFu);
    const int py = p / 24, px = p % 24;
    const float* WOFFT = (const float*)(wsb + WS_WOFFT);
    const float* B1OFF = (const float*)(wsb + WS_B1OFF);
    const float* W2OFF = (const float*)(wsb + WS_W2OFF);
    const float* B2OFF = (const float*)(wsb + WS_B2OFF);
    float ymid = 0.f;
    if (tl < 24){
      float s = 0.f;
      for (int ci = 0; ci < CIN; ++ci){
        const float* wv = WOFFT + ci*216 + tl;
        const float* xb = fb + ci*HW;
        #pragma unroll
        for (int k = 0; k < 9; ++k){
          const int yy = py + k/3 - 1, xx = px + k%3 - 1;
          if (yy >= 0 && yy < 24 && xx >= 0 && xx < 24)
            s = fmaf(xb[yy*24 + xx], wv[k*24], s);
        }
      }
      ymid = fmaxf(s + B1OFF[tl], 0.f);
    }
    float ox = B2OFF[2*n], oy = B2OFF[2*n + 1];
    for (int o = 0; o < 24; ++o){
      const float ym = __shfl(ymid, o, 32);
      ox = fmaf(ym, W2OFF[(2*n)*24 + o], ox);
      oy = fmaf(ym, W2OFF[(2*n + 1)*24 + o], oy);
    }
    if (tl == 0){
      const float fx = ((float)px + ox) * 4.f - 112.f;  // SCALE=4, X0=-112
      const float fy = ((float)py + oy) * 4.f;          // Y0=0
      out[O_NORM + b*8 + 2*n    ] = (fx + 112.f) * (1.f/336.f);
      out[O_NORM + b*8 + 2*n + 1] = fy * (1.f/224.f);
      out[O_PIX  + b*8 + 2*n    ] = fx;
      out[O_PIX  + b*8 + 2*n + 1] = fy;
    }
  }
}

// ---------------- launch ----------------
extern "C" void kernel_launch(void* const* d_in, const int* in_sizes, int n_in,
                              void* d_out, int out_size, void* d_ws, size_t ws_size,
                              hipStream_t stream)
{
  const float* feat = (const float*)d_in[0];
  P32 P;
  for (int h = 0; h < 4; ++h){
    const int base = 1 + h*8;
    P.w1[h] = (const float*)d_in[base+0];
    P.b1[h] = (const float*)d_in[base+1];
    P.g[h]  = (const float*)d_in[base+2];
    P.be[h] = (const float*)d_in[base+3];
    P.m[h]  = (const float*)d_in[base+4];
    P.v[h]  = (const float*)d_in[base+5];
    P.w2[h] = (const float*)d_in[base+6];
    P.b2[h] = (const float*)d_in[base+7];
  }
  char* wsb = (char*)d_ws;
  float* out = (float*)d_out;

  prep_kernel<<<dim3(1),   256, 0, stream>>>(P, wsb);
  conv_main  <<<dim3(NB),  576, 0, stream>>>(feat, wsb, out);
}